// Round 2
// baseline (385.264 us; speedup 1.0000x reference)
//
#include <hip/hip_runtime.h>

// UnrolledSIR: 364 days x 100 Euler substeps of the 3-state SIR ODE.
// Strictly serial recurrence -> single-thread, register-resident, latency-bound.
//
// Reformulated state (S, p=hb*I, R) shortens the serial dependence cycle:
//   r = fma(hb, S, c); S' = fma(-p, S, S); p' = p*r; R' = fma(hg/hb, p, R)
// Binding cycle S->r->p'->S'' = 3 dependence edges / 2 substeps (1.5*L per
// substep) vs 2*L for the naive (S,I) form.

#define N_DAYS 364
#define N_STEPS 100

__global__ __launch_bounds__(64) void sir_serial_kernel(
    const float* __restrict__ y0,
    const float* __restrict__ beta,
    float* __restrict__ out)
{
    if (threadIdx.x != 0) return;  // one lane runs the whole serial chain

    float S = y0[0];
    float I = y0[1];
    float R = y0[2];

    const float h      = 1.0f / 100.0f;   // matches jnp.float32(1.0/STEPS)
    const float b      = beta[0];         // beta[-1] on a 1-elem array
    const float hb     = h * b;
    const float hg     = h * 0.1f;        // h * GAMMA
    const float c      = 1.0f - hg;       // I' = I * (hb*S + (1-hg))
    const float kk     = hg / hb;         // R' = R + hg*I = R + (hg/hb)*p
    const float inv_hb = 1.0f / hb;       // day-end I = p * inv_hb

    float p = hb * I;                     // p = hb * I

    for (int day = 0; day < N_DAYS; ++day) {
        #pragma unroll
        for (int s = 0; s < N_STEPS; ++s) {
            float r = __builtin_fmaf(hb, S, c);   // r_n = hb*S_n + (1-hg)
            S = __builtin_fmaf(-p, S, S);         // S_{n+1} = S_n*(1 - p_n)
            R = __builtin_fmaf(kk, p, R);         // R_{n+1} = R_n + hg*I_n
            p = p * r;                            // p_{n+1} = p_n * r_n
        }
        // record end-of-day state; row d = state after (d+1) days
        out[3 * day + 0] = S;
        out[3 * day + 1] = p * inv_hb;            // I = p / hb
        out[3 * day + 2] = R;
    }
}

extern "C" void kernel_launch(void* const* d_in, const int* in_sizes, int n_in,
                              void* d_out, int out_size, void* d_ws, size_t ws_size,
                              hipStream_t stream) {
    const float* y0   = (const float*)d_in[0];  // 3 elems
    const float* beta = (const float*)d_in[1];  // 1 elem
    float* out = (float*)d_out;                 // 364*3 = 1092 f32

    sir_serial_kernel<<<dim3(1), dim3(64), 0, stream>>>(y0, beta, out);
}